// Round 7
// baseline (388.429 us; speedup 1.0000x reference)
//
#include <hip/hip_runtime.h>

#define O_DIM   1024
#define C_DIM   512
#define HW      784
#define B_DIM   32
#define T_POS   4                // 4 consecutive n per wg; 32KB LDS
#define NTILES  (HW / T_POS)     // 196
#define NTHREADS 128
#define NBLK    (B_DIM * NTILES) // 6272 = 8 * 784 (exact XCD chunking)
#define RPAD    5                // 5 coprime 32 -> conflict-free transpose

typedef float v2f __attribute__((ext_vector_type(2)));

// complex multiply via packed fp32: (a.x*b.x - a.y*b.y, a.x*b.y + a.y*b.x)
__device__ __forceinline__ v2f cmul(v2f a, v2f b) {
    v2f bs = __builtin_shufflevector(b, b, 1, 0);   // (b.y, b.x)
    v2f an = {-a.y, a.y};
    return a.x * b + an * bs;
}

static constexpr int REV5[32] = {
    0,16,8,24,4,20,12,28,2,18,10,26,6,22,14,30,
    1,17,9,25,5,21,13,29,3,19,11,27,7,23,15,31};

static constexpr float C32T[16] = {
    1.f, 0.98078528f, 0.92387953f, 0.83146961f,
    0.70710678f, 0.55557023f, 0.38268343f, 0.19509032f,
    0.f, -0.19509032f, -0.38268343f, -0.55557023f,
    -0.70710678f, -0.83146961f, -0.92387953f, -0.98078528f};
static constexpr float S32T[16] = {
    0.f, 0.19509032f, 0.38268343f, 0.55557023f,
    0.70710678f, 0.83146961f, 0.92387953f, 0.98078528f,
    1.f, 0.98078528f, 0.92387953f, 0.83146961f,
    0.70710678f, 0.55557023f, 0.38268343f, 0.19509032f};

// 32-point in-register DIF FFT, FORWARD only (inverse via conjugation).
// Input natural order; output y[i] = X[rev5(i)].
__device__ __forceinline__ void fft32f(v2f y[32]) {
#pragma unroll
    for (int s = 0; s < 5; ++s) {
        const int L = 32 >> s;
        const int h = 16 >> s;
#pragma unroll
        for (int u = 0; u < 16; ++u) {
            const int blk = u >> (4 - s);
            const int t   = u & (h - 1);
            const int i   = blk * L + t;
            const int m   = t << s;            // twiddle index: W32^m
            v2f a = y[i], b = y[i + h];
            y[i] = a + b;
            v2f d = a - b;
            if (m == 0) {
                y[i + h] = d;
            } else if (m == 8) {
                y[i + h] = (v2f){d.y, -d.x};   // * -i  (forward)
            } else {
                y[i + h] = cmul(d, (v2f){C32T[m], -S32T[m]});
            }
        }
    }
}

// Second half of the four-step (forward sign): y[rev5(k2)] = A[p][k2] on entry.
// Twiddle by W1024^(-p*k2) (4 chains, depth ~12), scatter to swizzled rows,
// same-half-wave transpose read, final fft32. Return: y[rev5(k1)] = X[p+32k1].
__device__ __forceinline__ void four_step_Bf(v2f* zg, int p, v2f y[32]) {
    float sv, cv;
    __sincosf(-6.283185307179586f * (float)p * (1.f / 1024.f), &sv, &cv);
    const v2f stw = {cv, sv};                    // W1024^(-p)
    v2f t2  = cmul(stw, stw);
    v2f t4  = cmul(t2, t2);
    v2f s8  = cmul(t4, t4);                      // stw^8
    v2f s16 = cmul(s8, s8);                      // stw^16
    v2f s24 = cmul(s16, s8);                     // stw^24
    v2f wq0 = {1.f, 0.f}, wq1 = s8, wq2 = s16, wq3 = s24;
#pragma unroll
    for (int m = 0; m < 8; ++m) {
        {   const int k2 = m;                     // chain 0
            v2f val = y[REV5[k2]];
            if (k2 > 0) val = cmul(val, wq0);
            zg[k2 * 32 + ((p + k2) & 31)] = val; }
        {   const int k2 = 8 + m;                 // chain 1
            zg[k2 * 32 + ((p + k2) & 31)] = cmul(y[REV5[k2]], wq1); }
        {   const int k2 = 16 + m;                // chain 2
            zg[k2 * 32 + ((p + k2) & 31)] = cmul(y[REV5[k2]], wq2); }
        {   const int k2 = 24 + m;                // chain 3
            zg[k2 * 32 + ((p + k2) & 31)] = cmul(y[REV5[k2]], wq3); }
        if (m < 7) {
            wq0 = cmul(wq0, stw); wq1 = cmul(wq1, stw);
            wq2 = cmul(wq2, stw); wq3 = cmul(wq3, stw);
        }
    }
    __builtin_amdgcn_wave_barrier();
#pragma unroll
    for (int n1 = 0; n1 < 32; ++n1)
        y[n1] = zg[p * 32 + ((n1 + p) & 31)];
    __builtin_amdgcn_wave_barrier();
    fft32f(y);
}

// One block per output row o; lanes sweep c coalesced. Each column c has
// exactly one nonzero across o, so the winning thread writes without races.
__global__ void extract_sketch(const float* __restrict__ sk1,
                               const float* __restrict__ sk2,
                               int* __restrict__ h, float* __restrict__ s) {
    const int o = blockIdx.x;                 // 0..1023
    for (int c = threadIdx.x; c < C_DIM; c += blockDim.x) {
        float v1 = sk1[o * C_DIM + c];
        if (v1 != 0.f) { h[c] = o; s[c] = v1; }
        float v2 = sk2[o * C_DIM + c];
        if (v2 != 0.f) { h[C_DIM + c] = o; s[C_DIM + c] = v2; }
    }
}

// bounds(128,4): waves-per-EU attr 2->4. Body byte-identical to the 222 us
// round-4 kernel; single-variable occupancy experiment (LDS allows 5 blocks,
// VGPR cap at 4/EU is 128 = exactly what the compiler used at bounds 2).
__global__ __launch_bounds__(NTHREADS, 4)
void cbp_main(const float* __restrict__ x1, const float* __restrict__ x2,
              const int* __restrict__ h1, const int* __restrict__ h2,
              const float* __restrict__ s1, const float* __restrict__ s2,
              float* __restrict__ out) {
    // 32 KB: Z = [4][1024] complex for scatter+FFT; after the FFTs die the
    // same space is reused as R = [1024][5] floats for the output transpose.
    __shared__ float4 LBUF[2048];
    float* Zs = reinterpret_cast<float*>(LBUF);    // scalar view (atomics)
    float* R  = reinterpret_cast<float*>(LBUF);    // transpose overlay

    const int tid = threadIdx.x;
    // chunked XCD swizzle (8 XCDs, 6272 = 8*784): consecutive work items
    // (same b, adjacent tiles) land on the SAME XCD so the 16B x-reads /
    // 16B out-writes that share a 64B line hit the same L2.
    const int wid  = blockIdx.x;
    const int work = (wid & 7) * (NBLK >> 3) + (wid >> 3);
    const int b    = work / NTILES;
    const int tile = work % NTILES;
    const int n0   = tile * T_POS;

    // ---- prefetch: 4 channel rows per thread, 16 B each ----
    const int xoff = b * (C_DIM * HW) + n0;
    float4 xa[4], xb[4];
    int    qa[4], qb[4];
    float  wa[4], wb[4];
#pragma unroll
    for (int r = 0; r < 4; ++r) {
        const int c = tid + NTHREADS * r;
        xa[r] = *(const float4*)(x1 + xoff + c * HW);
        xb[r] = *(const float4*)(x2 + xoff + c * HW);
        qa[r] = h1[c];  qb[r] = h2[c];
        wa[r] = s1[c];  wb[r] = s2[c];
    }

    // ---- zero LDS (hides the global-load latency) ----
#pragma unroll
    for (int i = 0; i < 2048 / NTHREADS; ++i)
        LBUF[tid + NTHREADS * i] = make_float4(0.f, 0.f, 0.f, 0.f);
    __syncthreads();

    // ---- scatter: Z[pos][h1[c]].x += s1*x1, Z[pos][h2[c]].y += s2*x2 ----
    // workgroup-scoped relaxed fp32 adds -> ds pipe atomic, no CAS loop.
#pragma unroll
    for (int r = 0; r < 4; ++r) {
        float va[4] = {xa[r].x, xa[r].y, xa[r].z, xa[r].w};
#pragma unroll
        for (int j = 0; j < 4; ++j)
            __hip_atomic_fetch_add(&Zs[(j * O_DIM + qa[r]) * 2 + 0],
                                   wa[r] * va[j],
                                   __ATOMIC_RELAXED, __HIP_MEMORY_SCOPE_WORKGROUP);
        float vb[4] = {xb[r].x, xb[r].y, xb[r].z, xb[r].w};
#pragma unroll
        for (int j = 0; j < 4; ++j)
            __hip_atomic_fetch_add(&Zs[(j * O_DIM + qb[r]) * 2 + 1],
                                   wb[r] * vb[j],
                                   __ATOMIC_RELAXED, __HIP_MEMORY_SCOPE_WORKGROUP);
    }
    __syncthreads();

    const int g    = tid >> 5;       // position group 0..3 (half-wave)
    const int p    = tid & 31;
    const int lane = tid & 63;
    v2f* zg = reinterpret_cast<v2f*>(LBUF) + g * O_DIM;
    const int paddr = (((lane & 32) | ((32 - p) & 31))) << 2;

    v2f y[32];

    // Two iterations of the SAME forward-FFT code path (code emitted once):
    //   iter 0: forward FFT of z = p1 + i*p2 from LDS
    //   iter 1: inverse FFT of the Hermitian product via the conjugation
    //           identity IFFT(G) = conj(FFT(conj(G))); conj folded into the
    //           product signs, final conj free (only .x stored).
#pragma unroll 1
    for (int iter = 0; iter < 2; ++iter) {
        if (iter == 0) {
#pragma unroll
            for (int n2 = 0; n2 < 32; ++n2)
                y[n2] = zg[p + 32 * n2];
            __builtin_amdgcn_wave_barrier();
        } else {
            // ---- Hermitian unpack + pointwise product, in registers ----
            // G[k], k = p+32*n2, needs zb = X[1024-k] from lane (32-p)&31,
            // reg REV5[31-n2] (p>=1): fixed half-wave pairing -> bpermute.
            // Lane 0 self-patches from reg REV5[(32-n2)&31].
            v2f t[32];
#pragma unroll
            for (int n2 = 0; n2 < 32; ++n2) {
                v2f za = y[REV5[n2]];
                v2f yb = y[REV5[31 - n2]];
                v2f zb;
                zb.x = __uint_as_float((unsigned)__builtin_amdgcn_ds_bpermute(
                           paddr, (int)__float_as_uint(yb.x)));
                zb.y = __uint_as_float((unsigned)__builtin_amdgcn_ds_bpermute(
                           paddr, (int)__float_as_uint(yb.y)));
                v2f self = y[REV5[(32 - n2) & 31]];
                zb.x = (p == 0) ? self.x : zb.x;
                zb.y = (p == 0) ? self.y : zb.y;
                v2f F1c = { za.x + zb.x, zb.y - za.y };   // conj(2*F1)
                v2f F2c = { za.y + zb.y, za.x - zb.x };   // conj(2*F2)
                t[n2] = cmul(F1c, F2c);                    // conj(4*G[k])
            }
#pragma unroll
            for (int i = 0; i < 32; ++i) y[i] = t[i];
        }
        fft32f(y);
        four_step_Bf(zg, p, y);
    }
    __syncthreads();              // all groups done with Z before R overlay

    // ---- stage transpose: R[o][g] = conv[pos g][bucket o] ----
#pragma unroll
    for (int k1 = 0; k1 < 32; ++k1)
        R[(p + 32 * k1) * RPAD + g] = y[REV5[k1]].x * (0.25f / 1024.f);
    __syncthreads();

    // ---- store: 16 B (4 consecutive n) per o ----
    const int obase = b * (O_DIM * HW) + n0;
#pragma unroll
    for (int r = 0; r < O_DIM / NTHREADS; ++r) {
        const int o = tid + NTHREADS * r;
        const float* rp = &R[o * RPAD];
        float4 v0 = make_float4(rp[0], rp[1], rp[2], rp[3]);
        *(float4*)(out + obase + o * HW) = v0;
    }
}

extern "C" void kernel_launch(void* const* d_in, const int* in_sizes, int n_in,
                              void* d_out, int out_size, void* d_ws, size_t ws_size,
                              hipStream_t stream) {
    const float* x1  = (const float*)d_in[0];
    const float* x2  = (const float*)d_in[1];
    const float* sk1 = (const float*)d_in[2];
    const float* sk2 = (const float*)d_in[3];
    float* out = (float*)d_out;

    int*   h = (int*)d_ws;                         // [0..511]=h1, [512..1023]=h2
    float* s = (float*)((char*)d_ws + 4096);       // [0..511]=s1, [512..1023]=s2

    hipLaunchKernelGGL(extract_sketch, dim3(O_DIM), dim3(256), 0, stream,
                       sk1, sk2, h, s);
    hipLaunchKernelGGL(cbp_main, dim3(NBLK), dim3(NTHREADS), 0, stream,
                       x1, x2, h, h + C_DIM, s, s + C_DIM, out);
}